// Round 1
// baseline (5082.078 us; speedup 1.0000x reference)
//
#include <hip/hip_runtime.h>
#include <math.h>

constexpr int N = 512;
constexpr int D = 16;
constexpr int E = 12;

// ---- workspace layout (float offsets) ----
constexpr size_t OFF_A     = 0;                            // E*N*N  (becomes Cholesky L in lower tri)
constexpr size_t OFF_IK    = OFF_A    + (size_t)E*N*N;     // E*N*N  (A^{-1})
constexpr size_t OFF_XS    = OFF_IK   + (size_t)E*N*N;     // N*D
constexpr size_t OFF_INP   = OFF_XS   + (size_t)N*D;       // N*D
constexpr size_t OFF_YN    = OFF_INP  + (size_t)N*D;       // E*N
constexpr size_t OFF_BETA  = OFF_YN   + (size_t)E*N;       // E*N
constexpr size_t OFF_KVEC  = OFF_BETA + (size_t)E*N;       // E*N
constexpr size_t OFF_LB    = OFF_KVEC + (size_t)E*N;       // E*N
constexpr size_t OFF_TIL   = OFF_LB   + (size_t)E*N;       // E*N*D
constexpr size_t OFF_X1    = OFF_TIL  + (size_t)E*N*D;     // E*N*D   X1[e,n,d] = inp/ls2
constexpr size_t OFF_X1Q   = OFF_X1   + (size_t)E*N*D;     // E*E*N*D
constexpr size_t OFF_XS1   = OFF_X1Q  + (size_t)E*E*N*D;   // E*E*N
constexpr size_t OFF_XS2   = OFF_XS1  + (size_t)E*E*N;     // E*E*N
constexpr size_t OFF_Q     = OFF_XS2  + (size_t)E*E*N;     // E*E*D*D
constexpr size_t OFF_BINV  = OFF_Q    + (size_t)E*E*D*D;   // E*D*D
constexpr size_t OFF_C     = OFF_BINV + (size_t)E*D*D;     // E
constexpr size_t OFF_ISDR  = OFF_C    + E;                 // E*E
constexpr size_t OFF_SPART = OFF_ISDR + E*E;               // E*E*32
constexpr size_t OFF_TPART = OFF_SPART+ (size_t)E*E*32;    // E*32
constexpr size_t OFF_XMEAN = OFF_TPART+ (size_t)E*32;      // D
constexpr size_t OFF_XSTD  = OFF_XMEAN+ D;                 // D
constexpr size_t OFF_YMEAN = OFF_XSTD + D;                 // E
constexpr size_t OFF_YSTD  = OFF_YMEAN+ E;                 // E
constexpr size_t OFF_SSM   = OFF_YSTD + E;                 // D*D (scaled s)

// ---------- 1. standardization ----------
__global__ __launch_bounds__(512) void k_prep(const float* __restrict__ X, const float* __restrict__ Y,
                                              const float* __restrict__ m, const float* __restrict__ s,
                                              float* __restrict__ ws) {
    int tid = threadIdx.x;  // 512 = N
    __shared__ float red[512];
    __shared__ float mean_s[D], std_s[D], ym_s[E], ys_s[E], mm_s[D];

    for (int d = 0; d < D; ++d) {
        float v = X[tid*D + d];
        red[tid] = v; __syncthreads();
        for (int o = 256; o > 0; o >>= 1) { if (tid < o) red[tid] += red[tid+o]; __syncthreads(); }
        float mean = red[0] * (1.0f/N);
        __syncthreads();
        red[tid] = v*v; __syncthreads();
        for (int o = 256; o > 0; o >>= 1) { if (tid < o) red[tid] += red[tid+o]; __syncthreads(); }
        if (tid == 0) { float var = (red[0] - (float)N*mean*mean) / (float)(N-1);
                        mean_s[d] = mean; std_s[d] = sqrtf(var); }
        __syncthreads();
    }
    for (int e = 0; e < E; ++e) {
        float v = Y[tid*E + e];
        red[tid] = v; __syncthreads();
        for (int o = 256; o > 0; o >>= 1) { if (tid < o) red[tid] += red[tid+o]; __syncthreads(); }
        float mean = red[0] * (1.0f/N);
        __syncthreads();
        red[tid] = v*v; __syncthreads();
        for (int o = 256; o > 0; o >>= 1) { if (tid < o) red[tid] += red[tid+o]; __syncthreads(); }
        if (tid == 0) { float var = (red[0] - (float)N*mean*mean) / (float)(N-1);
                        ym_s[e] = mean; ys_s[e] = sqrtf(var); }
        __syncthreads();
    }
    if (tid < D) {
        mm_s[tid] = (m[tid] - mean_s[tid]) / std_s[tid];
        ws[OFF_XMEAN + tid] = mean_s[tid];
        ws[OFF_XSTD  + tid] = std_s[tid];
    }
    if (tid < E) { ws[OFF_YMEAN + tid] = ym_s[tid]; ws[OFF_YSTD + tid] = ys_s[tid]; }
    __syncthreads();
    for (int d = 0; d < D; ++d) {
        float xs = (X[tid*D + d] - mean_s[d]) / std_s[d];
        ws[OFF_XS  + tid*D + d] = xs;
        ws[OFF_INP + tid*D + d] = xs - mm_s[d];
    }
    for (int e = 0; e < E; ++e)
        ws[OFF_YN + e*N + tid] = (Y[tid*E + e] - ym_s[e]) / ys_s[e];
    if (tid < D*D) {
        int i = tid / D, j = tid % D;
        ws[OFF_SSM + tid] = s[tid] / (std_s[i] * std_s[j]);
    }
}

// ---------- 2. A = K + noise I ----------
__global__ __launch_bounds__(256) void k_buildA(float* __restrict__ ws, const float* __restrict__ ls,
                                                const float* __restrict__ os, const float* __restrict__ noise) {
    int bid = blockIdx.x;            // E * 32 * 32
    int e  = bid >> 10;
    int t  = bid & 1023;
    int nt = t >> 5, mt = t & 31;
    int tid = threadIdx.x;
    int tn = tid >> 4, tm = tid & 15;
    __shared__ float xn[16][16], xm[16][16], il[16];
    int r = tid >> 4, d0 = tid & 15;
    xn[r][d0] = ws[OFF_XS + (size_t)(nt*16 + r)*D + d0];
    xm[r][d0] = ws[OFF_XS + (size_t)(mt*16 + r)*D + d0];
    if (tid < D) il[tid] = 1.0f / ls[e*D + tid];
    __syncthreads();
    float sq = 0.f;
    #pragma unroll
    for (int d = 0; d < D; ++d) { float df = (xn[tn][d] - xm[tm][d]) * il[d]; sq += df*df; }
    int n = nt*16 + tn, mcol = mt*16 + tm;
    float v = os[e] * __expf(-0.5f * sq);
    if (n == mcol) v += noise[e];
    ws[OFF_A + ((size_t)e*N + n)*N + mcol] = v;
}

// ---------- 3a. per-e Cholesky (in place, lower) ----------
__global__ __launch_bounds__(1024) void k_chol(float* __restrict__ ws) {
    int e = blockIdx.x;
    float* A = ws + OFF_A + (size_t)e*N*N;
    int tid = threadIdx.x;
    int tx = tid & 31, ty = tid >> 5;
    __shared__ float colk[N];
    __shared__ float dshare;
    for (int k = 0; k < N; ++k) {
        if (tid == 0) { float dv = sqrtf(A[(size_t)k*N + k]); A[(size_t)k*N + k] = dv; dshare = dv; }
        __syncthreads();
        float inv = 1.0f / dshare;
        for (int i = k+1+tid; i < N; i += 1024) {
            float v = A[(size_t)i*N + k] * inv;
            A[(size_t)i*N + k] = v;
            colk[i] = v;
        }
        __syncthreads();
        for (int i = k+1+ty; i < N; i += 32) {
            float ci = colk[i];
            for (int j = k+1+tx; j <= i; j += 32)
                A[(size_t)i*N + j] -= ci * colk[j];
        }
        __syncthreads();
    }
}

// ---------- 3b. iK = A^{-1} via L: fwd+bwd substitution, 32 RHS columns per block ----------
__global__ __launch_bounds__(512) void k_solve(float* __restrict__ ws) {
    int bid = blockIdx.x;            // E * 16
    int e  = bid >> 4;
    int c0 = (bid & 15) * 32;
    const float* A = ws + OFF_A + (size_t)e*N*N;
    float* IK = ws + OFF_IK + (size_t)e*N*N;
    int tid = threadIdx.x;
    int c = tid & 31, g = tid >> 5;  // 16 row-groups x 32 cols
    __shared__ float rhs[N*32];      // 64 KB
    for (int i = g; i < N; i += 16) rhs[i*32 + c] = (i == c0 + c) ? 1.f : 0.f;
    __syncthreads();
    // forward: L y = I (cols c0..c0+31); rows < c0 are zero so start at c0
    for (int k = c0; k < N; ++k) {
        if (g == 0) rhs[k*32 + c] /= A[(size_t)k*N + k];
        __syncthreads();
        float yk = rhs[k*32 + c];
        for (int i = k+1+g; i < N; i += 16) rhs[i*32 + c] -= A[(size_t)i*N + k] * yk;
        __syncthreads();
    }
    // backward: L^T x = y
    for (int k = N-1; k >= 0; --k) {
        if (g == 0) rhs[k*32 + c] /= A[(size_t)k*N + k];
        __syncthreads();
        float xk = rhs[k*32 + c];
        for (int i = g; i < k; i += 16) rhs[i*32 + c] -= A[(size_t)k*N + i] * xk;
        __syncthreads();
    }
    for (int i = g; i < N; i += 16) IK[(size_t)i*N + c0 + c] = rhs[i*32 + c];
}

// ---------- 3c. beta = iK @ Yn ----------
__global__ __launch_bounds__(256) void k_beta(float* __restrict__ ws) {
    int t = blockIdx.x*256 + threadIdx.x;   // E*N
    int e = t >> 9, n = t & 511;
    const float* IKrow = ws + OFF_IK + ((size_t)e*N + n)*N;
    const float* yn = ws + OFF_YN + (size_t)e*N;
    float acc = 0.f;
    for (int mm = 0; mm < N; ++mm) acc += IKrow[mm] * yn[mm];
    ws[OFF_BETA + e*N + n] = acc;
}

// ---------- 4a. B inverse + detB -> c ----------
__global__ __launch_bounds__(256) void k_B(float* __restrict__ ws, const float* __restrict__ ls,
                                           const float* __restrict__ os) {
    int e = blockIdx.x;
    int tid = threadIdx.x;
    int i = tid >> 4, j = tid & 15;
    __shared__ float Bm[16][17], Inv[16][17];
    float li = ls[e*D + i], lj = ls[e*D + j];
    Bm[i][j] = ws[OFF_SSM + i*D + j] / (li*lj) + ((i==j) ? 1.f : 0.f);
    Inv[i][j] = (i==j) ? 1.f : 0.f;
    __syncthreads();
    float det = 1.f;
    for (int k = 0; k < D; ++k) {
        float p   = Bm[k][k];
        float fik = Bm[i][k];
        float bkj = Bm[k][j];
        float ikj = Inv[k][j];
        __syncthreads();
        det *= p;
        if (i == k) { Bm[k][j] = bkj/p; Inv[k][j] = ikj/p; }
        else        { float f = fik/p; Bm[i][j] -= f*bkj; Inv[i][j] -= f*ikj; }
        __syncthreads();
    }
    ws[OFF_BINV + ((size_t)e*D + i)*D + j] = Inv[i][j];
    if (tid == 0) ws[OFF_C + e] = os[e] / sqrtf(det);
}

// ---------- 4b. R inverse, detR, Q = R^{-1} ss / 2 ----------
__global__ __launch_bounds__(256) void k_R(float* __restrict__ ws, const float* __restrict__ ls) {
    int pair = blockIdx.x;           // E*E
    int a = pair / E, b = pair % E;
    int tid = threadIdx.x;
    int i = tid >> 4, j = tid & 15;
    __shared__ float Rm[16][17], Inv[16][17], ssl[16][17];
    float la = ls[a*D + j], lb2 = ls[b*D + j];
    float rj = 1.f/(la*la) + 1.f/(lb2*lb2);
    float ssv = ws[OFF_SSM + i*D + j];
    ssl[i][j] = ssv;
    Rm[i][j] = ssv * rj + ((i==j) ? 1.f : 0.f);
    Inv[i][j] = (i==j) ? 1.f : 0.f;
    __syncthreads();
    float det = 1.f;
    for (int k = 0; k < D; ++k) {
        float p   = Rm[k][k];
        float fik = Rm[i][k];
        float rkj = Rm[k][j];
        float ikj = Inv[k][j];
        __syncthreads();
        det *= p;
        if (i == k) { Rm[k][j] = rkj/p; Inv[k][j] = ikj/p; }
        else        { float f = fik/p; Rm[i][j] -= f*rkj; Inv[i][j] -= f*ikj; }
        __syncthreads();
    }
    float q = 0.f;
    #pragma unroll
    for (int k2 = 0; k2 < D; ++k2) q += Inv[i][k2] * ssl[k2][j];
    ws[OFF_Q + ((size_t)pair*D + i)*D + j] = 0.5f * q;
    if (tid == 0) ws[OFF_ISDR + pair] = 1.f / sqrtf(det);
}

// ---------- 5. per (e,n): iN, t, lb, tiL, kvec, X1 ----------
__global__ __launch_bounds__(256) void k_point(float* __restrict__ ws, const float* __restrict__ ls,
                                               const float* __restrict__ os) {
    int t = blockIdx.x*256 + threadIdx.x;   // E*N
    int e = t >> 9, n = t & 511;
    float iN[D], tt[D], l[D];
    #pragma unroll
    for (int d = 0; d < D; ++d) { l[d] = ls[e*D + d]; iN[d] = ws[OFF_INP + n*D + d] / l[d]; }
    #pragma unroll
    for (int d = 0; d < D; ++d) {
        float acc = 0.f;
        #pragma unroll
        for (int j = 0; j < D; ++j) acc += ws[OFF_BINV + ((size_t)e*D + d)*D + j] * iN[j];
        tt[d] = acc;
    }
    float siNt = 0.f, siN2 = 0.f;
    #pragma unroll
    for (int d = 0; d < D; ++d) { siNt += iN[d]*tt[d]; siN2 += iN[d]*iN[d]; }
    float lbv = __expf(-0.5f * siNt) * ws[OFF_BETA + e*N + n];
    ws[OFF_LB + e*N + n] = lbv;
    #pragma unroll
    for (int d = 0; d < D; ++d) ws[OFF_TIL + ((size_t)e*N + n)*D + d] = tt[d] / l[d];
    ws[OFF_KVEC + e*N + n] = logf(os[e]) - 0.5f * siN2;
    #pragma unroll
    for (int d = 0; d < D; ++d) ws[OFF_X1 + ((size_t)e*N + n)*D + d] = ws[OFF_INP + n*D + d] / (l[d]*l[d]);
}

// ---------- 6. X1Q, Xs_, X2s per (a,b,n) ----------
__global__ __launch_bounds__(256) void k_x1q(float* __restrict__ ws) {
    int t = blockIdx.x*256 + threadIdx.x;   // E*E*N
    int pair = t / N, n = t % N;
    int a = pair / E, b = pair % E;
    __shared__ float Qs[16][16];
    Qs[threadIdx.x >> 4][threadIdx.x & 15] = ws[OFF_Q + (size_t)pair*D*D + threadIdx.x];
    __syncthreads();
    float x1a[D], x1b[D];
    #pragma unroll
    for (int d = 0; d < D; ++d) {
        x1a[d] = ws[OFF_X1 + ((size_t)a*N + n)*D + d];
        x1b[d] = ws[OFF_X1 + ((size_t)b*N + n)*D + d];
    }
    float xs1 = 0.f, xs2 = 0.f;
    #pragma unroll
    for (int j = 0; j < D; ++j) {
        float acc = 0.f, acc2 = 0.f;
        #pragma unroll
        for (int i = 0; i < D; ++i) { acc += x1a[i]*Qs[i][j]; acc2 += x1b[i]*Qs[i][j]; }
        ws[OFF_X1Q + ((size_t)pair*N + n)*D + j] = acc;
        xs1 += acc  * x1a[j];   // X1 Q X1
        xs2 += acc2 * x1b[j];   // X2 Q X2 (signs cancel)
    }
    ws[OFF_XS1 + (size_t)pair*N + n] = xs1;
    ws[OFF_XS2 + (size_t)pair*N + n] = xs2;
}

// ---------- 7. big cross-term: S partials + trace partials ----------
__global__ __launch_bounds__(256) void k_S(float* __restrict__ ws) {
    int bid = blockIdx.x;            // E*E*32
    int pair = bid >> 5, ntile = bid & 31;
    int a = pair / E, b = pair % E;
    int tid = threadIdx.x;
    int tn = tid >> 4, tm = tid & 15;
    __shared__ float x1q[16][17], x2t[16][17];
    __shared__ float ka[16], bea[16], xs1[16], kb[16], beb[16], xs2[16];
    __shared__ float red[256];
    int n = ntile*16 + tn;
    {
        int r = tid >> 4, d0 = tid & 15;
        x1q[r][d0] = ws[OFF_X1Q + ((size_t)pair*N + ntile*16 + r)*D + d0];
        if (tid < 16) {
            int nn = ntile*16 + tid;
            ka[tid]  = ws[OFF_KVEC + a*N + nn];
            bea[tid] = ws[OFF_BETA + a*N + nn];
            xs1[tid] = ws[OFF_XS1 + (size_t)pair*N + nn];
        }
    }
    float acc = 0.f, accT = 0.f;
    const float* IKrow = ws + OFF_IK + ((size_t)a*N + n)*N;
    for (int mt = 0; mt < 32; ++mt) {
        __syncthreads();
        int r = tid >> 4, d0 = tid & 15;
        x2t[r][d0] = ws[OFF_X1 + ((size_t)b*N + mt*16 + r)*D + d0];   // X1[b]; X2 = -this
        if (tid < 16) {
            int mmm = mt*16 + tid;
            kb[tid]  = ws[OFF_KVEC + b*N + mmm];
            beb[tid] = ws[OFF_BETA + b*N + mmm];
            xs2[tid] = ws[OFF_XS2 + (size_t)pair*N + mmm];
        }
        __syncthreads();
        float dot = 0.f;
        #pragma unroll
        for (int d = 0; d < D; ++d) dot += x1q[tn][d] * x2t[tm][d];
        // maha = -2*X1Q.X2 + Xs_ + X2s ; X2 = -X1[b]  =>  +2*dot
        float maha = 2.f*dot + xs1[tn] + xs2[tm];
        float Lv = __expf(ka[tn] + kb[tm] + maha);
        acc += bea[tn] * Lv * beb[tm];
        if (a == b) accT += IKrow[mt*16 + tm] * Lv;
    }
    red[tid] = acc; __syncthreads();
    for (int o = 128; o > 0; o >>= 1) { if (tid < o) red[tid] += red[tid+o]; __syncthreads(); }
    if (tid == 0) ws[OFF_SPART + bid] = red[0];
    if (a == b) {
        __syncthreads();
        red[tid] = accT; __syncthreads();
        for (int o = 128; o > 0; o >>= 1) { if (tid < o) red[tid] += red[tid+o]; __syncthreads(); }
        if (tid == 0) ws[OFF_TPART + a*32 + ntile] = red[0];
    }
}

// ---------- 8. finalize ----------
__global__ __launch_bounds__(256) void k_final(float* __restrict__ ws, const float* __restrict__ s,
                                               const float* __restrict__ os, float* __restrict__ out) {
    int tid = threadIdx.x;  // 256
    __shared__ float red[256];
    __shared__ float Msh[E], Vsh[E][D], cov[D][E+1];
    __shared__ float Sm[16][17], Si[16][17];

    for (int e = 0; e < E; ++e) {
        float p = 0.f;
        for (int n = tid; n < N; n += 256) p += ws[OFF_LB + e*N + n];
        red[tid] = p; __syncthreads();
        for (int o = 128; o > 0; o >>= 1) { if (tid < o) red[tid] += red[tid+o]; __syncthreads(); }
        if (tid == 0) Msh[e] = ws[OFF_C + e] * red[0];
        __syncthreads();
    }
    if (tid < E*D) {
        int e = tid / D, d = tid % D;
        float acc = 0.f;
        for (int n = 0; n < N; ++n)
            acc += ws[OFF_TIL + ((size_t)e*N + n)*D + d] * ws[OFF_LB + e*N + n];
        Vsh[e][d] = ws[OFF_C + e] * acc;
    }
    __syncthreads();

    if (tid < E*E) {
        int a = tid / E, bb = tid % E;
        float acc = 0.f;
        for (int q = 0; q < 32; ++q) acc += ws[OFF_SPART + (size_t)tid*32 + q];
        if (a == bb) {
            float tr = 0.f;
            for (int q = 0; q < 32; ++q) tr += ws[OFF_TPART + a*32 + q];
            acc -= tr;
        }
        acc *= ws[OFF_ISDR + tid];
        if (a == bb) acc += os[a];
        float v = acc - Msh[a]*Msh[bb];
        v *= ws[OFF_YSTD + a] * ws[OFF_YSTD + bb];
        out[E + tid] = v;                                // S
    }
    if (tid < E) out[tid] = Msh[tid]*ws[OFF_YSTD + tid] + ws[OFF_YMEAN + tid];  // Mout

    if (tid < D*E) {
        int d = tid / E, e = tid % E;
        float acc = 0.f;
        for (int k = 0; k < D; ++k) acc += ws[OFF_SSM + d*D + k] * Vsh[e][k];
        cov[d][e] = acc * ws[OFF_XSTD + d] * ws[OFF_YSTD + e];
    }
    // invert s (original) via GJ
    int i = tid >> 4, j = tid & 15;
    Sm[i][j] = s[i*D + j];
    Si[i][j] = (i==j) ? 1.f : 0.f;
    __syncthreads();
    for (int k = 0; k < D; ++k) {
        float p   = Sm[k][k];
        float fik = Sm[i][k];
        float skj = Sm[k][j];
        float ikj = Si[k][j];
        __syncthreads();
        if (i == k) { Sm[k][j] = skj/p; Si[k][j] = ikj/p; }
        else        { float f = fik/p; Sm[i][j] -= f*skj; Si[i][j] -= f*ikj; }
        __syncthreads();
    }
    if (tid < D*E) {
        int d = tid / E, e = tid % E;
        float acc = 0.f;
        for (int k = 0; k < D; ++k) acc += Si[d][k] * cov[k][e];
        out[E + E*E + d*E + e] = acc;                    // Vout
    }
}

extern "C" void kernel_launch(void* const* d_in, const int* in_sizes, int n_in,
                              void* d_out, int out_size, void* d_ws, size_t ws_size,
                              hipStream_t stream) {
    const float* X     = (const float*)d_in[0];
    const float* Y     = (const float*)d_in[1];
    const float* m     = (const float*)d_in[2];
    const float* s     = (const float*)d_in[3];
    const float* ls    = (const float*)d_in[4];
    const float* os    = (const float*)d_in[5];
    const float* noise = (const float*)d_in[6];
    float* ws  = (float*)d_ws;
    float* out = (float*)d_out;

    k_prep  <<<1,            512, 0, stream>>>(X, Y, m, s, ws);
    k_buildA<<<E*32*32,      256, 0, stream>>>(ws, ls, os, noise);
    k_chol  <<<E,           1024, 0, stream>>>(ws);
    k_solve <<<E*16,         512, 0, stream>>>(ws);
    k_beta  <<<E*N/256,      256, 0, stream>>>(ws);
    k_B     <<<E,            256, 0, stream>>>(ws, ls, os);
    k_R     <<<E*E,          256, 0, stream>>>(ws, ls);
    k_point <<<E*N/256,      256, 0, stream>>>(ws, ls, os);
    k_x1q   <<<E*E*N/256,    256, 0, stream>>>(ws);
    k_S     <<<E*E*32,       256, 0, stream>>>(ws);
    k_final <<<1,            256, 0, stream>>>(ws, s, os, out);
}

// Round 2
// 1621.483 us; speedup vs baseline: 3.1342x; 3.1342x over previous
//
#include <hip/hip_runtime.h>
#include <math.h>

constexpr int N = 512;
constexpr int D = 16;
constexpr int E = 12;

// ---- workspace layout (float offsets) ----
// OFF_A:  A -> L (Cholesky) -> iK (after SYRK)
// OFF_IK: W = L^{-1} (triangular inverse scratch)
constexpr size_t OFF_A     = 0;                            // E*N*N
constexpr size_t OFF_IK    = OFF_A    + (size_t)E*N*N;     // E*N*N
constexpr size_t OFF_XS    = OFF_IK   + (size_t)E*N*N;     // N*D
constexpr size_t OFF_INP   = OFF_XS   + (size_t)N*D;       // N*D
constexpr size_t OFF_YN    = OFF_INP  + (size_t)N*D;       // E*N
constexpr size_t OFF_BETA  = OFF_YN   + (size_t)E*N;       // E*N
constexpr size_t OFF_KVEC  = OFF_BETA + (size_t)E*N;       // E*N
constexpr size_t OFF_LB    = OFF_KVEC + (size_t)E*N;       // E*N
constexpr size_t OFF_TIL   = OFF_LB   + (size_t)E*N;       // E*N*D
constexpr size_t OFF_X1    = OFF_TIL  + (size_t)E*N*D;     // E*N*D
constexpr size_t OFF_X1Q   = OFF_X1   + (size_t)E*N*D;     // E*E*N*D
constexpr size_t OFF_XS1   = OFF_X1Q  + (size_t)E*E*N*D;   // E*E*N
constexpr size_t OFF_XS2   = OFF_XS1  + (size_t)E*E*N;     // E*E*N
constexpr size_t OFF_Q     = OFF_XS2  + (size_t)E*E*N;     // E*E*D*D
constexpr size_t OFF_BINV  = OFF_Q    + (size_t)E*E*D*D;   // E*D*D
constexpr size_t OFF_C     = OFF_BINV + (size_t)E*D*D;     // E
constexpr size_t OFF_ISDR  = OFF_C    + E;                 // E*E
constexpr size_t OFF_SPART = OFF_ISDR + E*E;               // E*E*32
constexpr size_t OFF_TPART = OFF_SPART+ (size_t)E*E*32;    // E*32
constexpr size_t OFF_XMEAN = OFF_TPART+ (size_t)E*32;      // D
constexpr size_t OFF_XSTD  = OFF_XMEAN+ D;                 // D
constexpr size_t OFF_YMEAN = OFF_XSTD + D;                 // E
constexpr size_t OFF_YSTD  = OFF_YMEAN+ E;                 // E
constexpr size_t OFF_SSM   = OFF_YSTD + E;                 // D*D

// ---------- 1. standardization ----------
__global__ __launch_bounds__(512) void k_prep(const float* __restrict__ X, const float* __restrict__ Y,
                                              const float* __restrict__ m, const float* __restrict__ s,
                                              float* __restrict__ ws) {
    int tid = threadIdx.x;  // 512 = N
    __shared__ float red[512];
    __shared__ float mean_s[D], std_s[D], ym_s[E], ys_s[E], mm_s[D];

    for (int d = 0; d < D; ++d) {
        float v = X[tid*D + d];
        red[tid] = v; __syncthreads();
        for (int o = 256; o > 0; o >>= 1) { if (tid < o) red[tid] += red[tid+o]; __syncthreads(); }
        float mean = red[0] * (1.0f/N);
        __syncthreads();
        red[tid] = v*v; __syncthreads();
        for (int o = 256; o > 0; o >>= 1) { if (tid < o) red[tid] += red[tid+o]; __syncthreads(); }
        if (tid == 0) { float var = (red[0] - (float)N*mean*mean) / (float)(N-1);
                        mean_s[d] = mean; std_s[d] = sqrtf(var); }
        __syncthreads();
    }
    for (int e = 0; e < E; ++e) {
        float v = Y[tid*E + e];
        red[tid] = v; __syncthreads();
        for (int o = 256; o > 0; o >>= 1) { if (tid < o) red[tid] += red[tid+o]; __syncthreads(); }
        float mean = red[0] * (1.0f/N);
        __syncthreads();
        red[tid] = v*v; __syncthreads();
        for (int o = 256; o > 0; o >>= 1) { if (tid < o) red[tid] += red[tid+o]; __syncthreads(); }
        if (tid == 0) { float var = (red[0] - (float)N*mean*mean) / (float)(N-1);
                        ym_s[e] = mean; ys_s[e] = sqrtf(var); }
        __syncthreads();
    }
    if (tid < D) {
        mm_s[tid] = (m[tid] - mean_s[tid]) / std_s[tid];
        ws[OFF_XMEAN + tid] = mean_s[tid];
        ws[OFF_XSTD  + tid] = std_s[tid];
    }
    if (tid < E) { ws[OFF_YMEAN + tid] = ym_s[tid]; ws[OFF_YSTD + tid] = ys_s[tid]; }
    __syncthreads();
    for (int d = 0; d < D; ++d) {
        float xs = (X[tid*D + d] - mean_s[d]) / std_s[d];
        ws[OFF_XS  + tid*D + d] = xs;
        ws[OFF_INP + tid*D + d] = xs - mm_s[d];
    }
    for (int e = 0; e < E; ++e)
        ws[OFF_YN + e*N + tid] = (Y[tid*E + e] - ym_s[e]) / ys_s[e];
    if (tid < D*D) {
        int i = tid / D, j = tid % D;
        ws[OFF_SSM + tid] = s[tid] / (std_s[i] * std_s[j]);
    }
}

// ---------- 2. A = K + noise I ----------
__global__ __launch_bounds__(256) void k_buildA(float* __restrict__ ws, const float* __restrict__ ls,
                                                const float* __restrict__ os, const float* __restrict__ noise) {
    int bid = blockIdx.x;            // E * 32 * 32
    int e  = bid >> 10;
    int t  = bid & 1023;
    int nt = t >> 5, mt = t & 31;
    int tid = threadIdx.x;
    int tn = tid >> 4, tm = tid & 15;
    __shared__ float xn[16][16], xm[16][16], il[16];
    int r = tid >> 4, d0 = tid & 15;
    xn[r][d0] = ws[OFF_XS + (size_t)(nt*16 + r)*D + d0];
    xm[r][d0] = ws[OFF_XS + (size_t)(mt*16 + r)*D + d0];
    if (tid < D) il[tid] = 1.0f / ls[e*D + tid];
    __syncthreads();
    float sq = 0.f;
    #pragma unroll
    for (int d = 0; d < D; ++d) { float df = (xn[tn][d] - xm[tm][d]) * il[d]; sq += df*df; }
    int n = nt*16 + tn, mcol = mt*16 + tm;
    float v = os[e] * __expf(-0.5f * sq);
    if (n == mcol) v += noise[e];
    ws[OFF_A + ((size_t)e*N + n)*N + mcol] = v;
}

// ---------- 3a. blocked Cholesky: panel factor (diag block in LDS + row solves) ----------
__global__ __launch_bounds__(256) void k_panel(float* __restrict__ ws, int k0) {
    int e = blockIdx.x;
    int tid = threadIdx.x;
    float* A = ws + OFF_A + (size_t)e*N*N;
    __shared__ float LD[64][65];
    __shared__ float invd;
    for (int idx = tid; idx < 64*64; idx += 256) {
        int r = idx >> 6, c = idx & 63;
        LD[r][c] = A[(size_t)(k0+r)*N + k0 + c];
    }
    __syncthreads();
    for (int j = 0; j < 64; ++j) {
        if (tid == 0) { float dv = sqrtf(LD[j][j]); LD[j][j] = dv; invd = 1.0f/dv; }
        __syncthreads();
        float iv = invd;
        for (int r = j+1+tid; r < 64; r += 256) LD[r][j] *= iv;
        __syncthreads();
        for (int idx = tid; idx < 64*64; idx += 256) {
            int r = idx >> 6, c = idx & 63;
            if (c > j && c <= r) LD[r][c] -= LD[r][j] * LD[c][j];
        }
        __syncthreads();
    }
    // write back diag block
    for (int idx = tid; idx < 64*64; idx += 256) {
        int r = idx >> 6, c = idx & 63;
        A[(size_t)(k0+r)*N + k0 + c] = LD[r][c];
    }
    // panel row solves: x * LD^T = a, one row per thread, fully unrolled in regs
    for (int r0 = k0 + 64 + tid; r0 < N; r0 += 256) {
        float x[64];
        #pragma unroll
        for (int c = 0; c < 64; ++c) x[c] = A[(size_t)r0*N + k0 + c];
        #pragma unroll
        for (int j = 0; j < 64; ++j) {
            float acc = x[j];
            #pragma unroll
            for (int i = 0; i < j; ++i) acc -= x[i] * LD[j][i];
            x[j] = acc / LD[j][j];
        }
        #pragma unroll
        for (int c = 0; c < 64; ++c) A[(size_t)r0*N + k0 + c] = x[c];
    }
}

// ---------- 3b. trailing SYRK update: A[tile] -= P_r P_c^T ----------
__global__ __launch_bounds__(256) void k_trail(float* __restrict__ ws, int k0) {
    int t0 = k0 + 64;
    int nb = (N - t0) >> 6;
    int ntiles = (nb*(nb+1)) >> 1;
    int e = blockIdx.x / ntiles;
    int t = blockIdx.x % ntiles;
    int bj = 0; while (t >= nb - bj) { t -= nb - bj; ++bj; }
    int bi = bj + t;
    float* A = ws + OFF_A + (size_t)e*N*N;
    const float* Pr = A + (size_t)(t0 + bi*64)*N + k0;
    const float* Pc = A + (size_t)(t0 + bj*64)*N + k0;
    __shared__ float Sr[64][65], Sc[64][65];
    int tid = threadIdx.x;
    for (int idx = tid; idx < 4096; idx += 256) {
        int r = idx >> 6, c = idx & 63;
        Sr[r][c] = Pr[(size_t)r*N + c];
        Sc[r][c] = Pc[(size_t)r*N + c];
    }
    __syncthreads();
    int tx = tid & 15, ty = tid >> 4;
    float acc[4][4] = {};
    #pragma unroll 8
    for (int p = 0; p < 64; ++p) {
        float ar[4], ac[4];
        #pragma unroll
        for (int q = 0; q < 4; ++q) { ar[q] = Sr[ty*4+q][p]; ac[q] = Sc[tx*4+q][p]; }
        #pragma unroll
        for (int q = 0; q < 4; ++q)
            #pragma unroll
            for (int w = 0; w < 4; ++w) acc[q][w] += ar[q]*ac[w];
    }
    float* Out = A + (size_t)(t0 + bi*64)*N + (t0 + bj*64);
    #pragma unroll
    for (int q = 0; q < 4; ++q)
        #pragma unroll
        for (int w = 0; w < 4; ++w)
            Out[(size_t)(ty*4+q)*N + tx*4+w] -= acc[q][w];
}

// ---------- 3c. triangular inverse W = L^{-1}: diagonal 64x64 blocks ----------
__global__ __launch_bounds__(64) void k_tinv_diag(float* __restrict__ ws) {
    int e = blockIdx.x >> 3;
    int j = blockIdx.x & 7;
    const float* L = ws + OFF_A  + (size_t)e*N*N;
    float*       W = ws + OFF_IK + (size_t)e*N*N;
    int c = threadIdx.x;  // column of the inverse, 64 threads
    __shared__ float LD[64][65];
    __shared__ float invd[64];
    for (int idx = c; idx < 4096; idx += 64) {
        int r = idx >> 6, cc = idx & 63;
        LD[r][cc] = L[(size_t)(j*64+r)*N + j*64+cc];
    }
    __syncthreads();
    invd[c] = 1.0f / LD[c][c];
    __syncthreads();
    float x[64];
    #pragma unroll
    for (int r = 0; r < 64; ++r) {
        float acc = (r == c) ? 1.0f : 0.0f;
        #pragma unroll
        for (int k = 0; k < r; ++k) acc -= LD[r][k] * x[k];
        x[r] = acc * invd[r];
    }
    #pragma unroll
    for (int r = 0; r < 64; ++r)
        W[(size_t)(j*64+r)*N + j*64 + c] = x[r];   // zeros above diagonal included
}

// ---------- 3d. triangular inverse off-diagonal wavefront d: W_ij = -W_ii (sum_k L_ik W_kj) ----------
__global__ __launch_bounds__(256) void k_tinv_off(float* __restrict__ ws, int d) {
    int e = blockIdx.x / (8 - d);
    int j = blockIdx.x % (8 - d);
    int i = j + d;
    const float* L = ws + OFF_A  + (size_t)e*N*N;
    float*       W = ws + OFF_IK + (size_t)e*N*N;
    __shared__ float Sa[64][65], Sb[64][65], T[64][65];
    int tid = threadIdx.x;
    int tx = tid & 15, ty = tid >> 4;
    float acc[4][4] = {};
    for (int k = j; k < i; ++k) {
        for (int idx = tid; idx < 4096; idx += 256) {
            int r = idx >> 6, cc = idx & 63;
            Sa[r][cc] = L[(size_t)(i*64+r)*N + k*64+cc];
            Sb[r][cc] = W[(size_t)(k*64+r)*N + j*64+cc];
        }
        __syncthreads();
        #pragma unroll 8
        for (int p = 0; p < 64; ++p) {
            float ar[4], ac[4];
            #pragma unroll
            for (int q = 0; q < 4; ++q) { ar[q] = Sa[ty*4+q][p]; ac[q] = Sb[p][tx*4+q]; }
            #pragma unroll
            for (int q = 0; q < 4; ++q)
                #pragma unroll
                for (int w = 0; w < 4; ++w) acc[q][w] += ar[q]*ac[w];
        }
        __syncthreads();
    }
    #pragma unroll
    for (int q = 0; q < 4; ++q)
        #pragma unroll
        for (int w = 0; w < 4; ++w) T[ty*4+q][tx*4+w] = acc[q][w];
    for (int idx = tid; idx < 4096; idx += 256) {
        int r = idx >> 6, cc = idx & 63;
        Sa[r][cc] = W[(size_t)(i*64+r)*N + i*64+cc];   // W_ii
    }
    __syncthreads();
    float o[4][4] = {};
    #pragma unroll 8
    for (int p = 0; p < 64; ++p) {
        float ar[4], ac[4];
        #pragma unroll
        for (int q = 0; q < 4; ++q) { ar[q] = Sa[ty*4+q][p]; ac[q] = T[p][tx*4+q]; }
        #pragma unroll
        for (int q = 0; q < 4; ++q)
            #pragma unroll
            for (int w = 0; w < 4; ++w) o[q][w] += ar[q]*ac[w];
    }
    #pragma unroll
    for (int q = 0; q < 4; ++q)
        #pragma unroll
        for (int w = 0; w < 4; ++w)
            W[(size_t)(i*64+ty*4+q)*N + j*64+tx*4+w] = -o[q][w];
}

// ---------- 3e. iK = W^T W (writes into OFF_A region, full symmetric) ----------
__global__ __launch_bounds__(256) void k_syrk(float* __restrict__ ws) {
    int e = blockIdx.x / 36;
    int t = blockIdx.x % 36;
    int bj = 0; while (t >= 8 - bj) { t -= 8 - bj; ++bj; }
    int bi = bj + t;                       // bi >= bj
    const float* W = ws + OFF_IK + (size_t)e*N*N;
    float*      IK = ws + OFF_A  + (size_t)e*N*N;
    __shared__ float Sa[64][65], Sb[64][65];
    int tid = threadIdx.x;
    int tx = tid & 15, ty = tid >> 4;
    float acc[4][4] = {};
    for (int p = bi; p < 8; ++p) {
        for (int idx = tid; idx < 4096; idx += 256) {
            int r = idx >> 6, cc = idx & 63;
            Sa[r][cc] = W[(size_t)(p*64+r)*N + bi*64+cc];
            Sb[r][cc] = W[(size_t)(p*64+r)*N + bj*64+cc];
        }
        __syncthreads();
        #pragma unroll 8
        for (int pr = 0; pr < 64; ++pr) {
            float ar[4], ac[4];
            #pragma unroll
            for (int q = 0; q < 4; ++q) { ar[q] = Sa[pr][ty*4+q]; ac[q] = Sb[pr][tx*4+q]; }
            #pragma unroll
            for (int q = 0; q < 4; ++q)
                #pragma unroll
                for (int w = 0; w < 4; ++w) acc[q][w] += ar[q]*ac[w];
        }
        __syncthreads();
    }
    #pragma unroll
    for (int q = 0; q < 4; ++q)
        #pragma unroll
        for (int w = 0; w < 4; ++w) {
            int r = bi*64 + ty*4 + q, c = bj*64 + tx*4 + w;
            IK[(size_t)r*N + c] = acc[q][w];
            IK[(size_t)c*N + r] = acc[q][w];
        }
}

// ---------- 3f. beta = iK @ Yn ----------
__global__ __launch_bounds__(256) void k_beta(float* __restrict__ ws) {
    int t = blockIdx.x*256 + threadIdx.x;   // E*N
    int e = t >> 9, n = t & 511;
    const float* IKrow = ws + OFF_A + ((size_t)e*N + n)*N;
    const float* yn = ws + OFF_YN + (size_t)e*N;
    float acc = 0.f;
    for (int mm = 0; mm < N; ++mm) acc += IKrow[mm] * yn[mm];
    ws[OFF_BETA + e*N + n] = acc;
}

// ---------- 4a. B inverse + detB -> c ----------
__global__ __launch_bounds__(256) void k_B(float* __restrict__ ws, const float* __restrict__ ls,
                                           const float* __restrict__ os) {
    int e = blockIdx.x;
    int tid = threadIdx.x;
    int i = tid >> 4, j = tid & 15;
    __shared__ float Bm[16][17], Inv[16][17];
    float li = ls[e*D + i], lj = ls[e*D + j];
    Bm[i][j] = ws[OFF_SSM + i*D + j] / (li*lj) + ((i==j) ? 1.f : 0.f);
    Inv[i][j] = (i==j) ? 1.f : 0.f;
    __syncthreads();
    float det = 1.f;
    for (int k = 0; k < D; ++k) {
        float p   = Bm[k][k];
        float fik = Bm[i][k];
        float bkj = Bm[k][j];
        float ikj = Inv[k][j];
        __syncthreads();
        det *= p;
        if (i == k) { Bm[k][j] = bkj/p; Inv[k][j] = ikj/p; }
        else        { float f = fik/p; Bm[i][j] -= f*bkj; Inv[i][j] -= f*ikj; }
        __syncthreads();
    }
    ws[OFF_BINV + ((size_t)e*D + i)*D + j] = Inv[i][j];
    if (tid == 0) ws[OFF_C + e] = os[e] / sqrtf(det);
}

// ---------- 4b. R inverse, detR, Q = R^{-1} ss / 2 ----------
__global__ __launch_bounds__(256) void k_R(float* __restrict__ ws, const float* __restrict__ ls) {
    int pair = blockIdx.x;           // E*E
    int a = pair / E, b = pair % E;
    int tid = threadIdx.x;
    int i = tid >> 4, j = tid & 15;
    __shared__ float Rm[16][17], Inv[16][17], ssl[16][17];
    float la = ls[a*D + j], lb2 = ls[b*D + j];
    float rj = 1.f/(la*la) + 1.f/(lb2*lb2);
    float ssv = ws[OFF_SSM + i*D + j];
    ssl[i][j] = ssv;
    Rm[i][j] = ssv * rj + ((i==j) ? 1.f : 0.f);
    Inv[i][j] = (i==j) ? 1.f : 0.f;
    __syncthreads();
    float det = 1.f;
    for (int k = 0; k < D; ++k) {
        float p   = Rm[k][k];
        float fik = Rm[i][k];
        float rkj = Rm[k][j];
        float ikj = Inv[k][j];
        __syncthreads();
        det *= p;
        if (i == k) { Rm[k][j] = rkj/p; Inv[k][j] = ikj/p; }
        else        { float f = fik/p; Rm[i][j] -= f*rkj; Inv[i][j] -= f*ikj; }
        __syncthreads();
    }
    float q = 0.f;
    #pragma unroll
    for (int k2 = 0; k2 < D; ++k2) q += Inv[i][k2] * ssl[k2][j];
    ws[OFF_Q + ((size_t)pair*D + i)*D + j] = 0.5f * q;
    if (tid == 0) ws[OFF_ISDR + pair] = 1.f / sqrtf(det);
}

// ---------- 5. per (e,n): iN, t, lb, tiL, kvec, X1 ----------
__global__ __launch_bounds__(256) void k_point(float* __restrict__ ws, const float* __restrict__ ls,
                                               const float* __restrict__ os) {
    int t = blockIdx.x*256 + threadIdx.x;   // E*N
    int e = t >> 9, n = t & 511;
    float iN[D], tt[D], l[D];
    #pragma unroll
    for (int d = 0; d < D; ++d) { l[d] = ls[e*D + d]; iN[d] = ws[OFF_INP + n*D + d] / l[d]; }
    #pragma unroll
    for (int d = 0; d < D; ++d) {
        float acc = 0.f;
        #pragma unroll
        for (int j = 0; j < D; ++j) acc += ws[OFF_BINV + ((size_t)e*D + d)*D + j] * iN[j];
        tt[d] = acc;
    }
    float siNt = 0.f, siN2 = 0.f;
    #pragma unroll
    for (int d = 0; d < D; ++d) { siNt += iN[d]*tt[d]; siN2 += iN[d]*iN[d]; }
    float lbv = __expf(-0.5f * siNt) * ws[OFF_BETA + e*N + n];
    ws[OFF_LB + e*N + n] = lbv;
    #pragma unroll
    for (int d = 0; d < D; ++d) ws[OFF_TIL + ((size_t)e*N + n)*D + d] = tt[d] / l[d];
    ws[OFF_KVEC + e*N + n] = logf(os[e]) - 0.5f * siN2;
    #pragma unroll
    for (int d = 0; d < D; ++d) ws[OFF_X1 + ((size_t)e*N + n)*D + d] = ws[OFF_INP + n*D + d] / (l[d]*l[d]);
}

// ---------- 6. X1Q, Xs_, X2s per (a,b,n) ----------
__global__ __launch_bounds__(256) void k_x1q(float* __restrict__ ws) {
    int t = blockIdx.x*256 + threadIdx.x;   // E*E*N
    int pair = t / N, n = t % N;
    int a = pair / E, b = pair % E;
    __shared__ float Qs[16][16];
    Qs[threadIdx.x >> 4][threadIdx.x & 15] = ws[OFF_Q + (size_t)pair*D*D + threadIdx.x];
    __syncthreads();
    float x1a[D], x1b[D];
    #pragma unroll
    for (int d = 0; d < D; ++d) {
        x1a[d] = ws[OFF_X1 + ((size_t)a*N + n)*D + d];
        x1b[d] = ws[OFF_X1 + ((size_t)b*N + n)*D + d];
    }
    float xs1 = 0.f, xs2 = 0.f;
    #pragma unroll
    for (int j = 0; j < D; ++j) {
        float acc = 0.f, acc2 = 0.f;
        #pragma unroll
        for (int i = 0; i < D; ++i) { acc += x1a[i]*Qs[i][j]; acc2 += x1b[i]*Qs[i][j]; }
        ws[OFF_X1Q + ((size_t)pair*N + n)*D + j] = acc;
        xs1 += acc  * x1a[j];
        xs2 += acc2 * x1b[j];
    }
    ws[OFF_XS1 + (size_t)pair*N + n] = xs1;
    ws[OFF_XS2 + (size_t)pair*N + n] = xs2;
}

// ---------- 7. big cross-term: S partials + trace partials ----------
__global__ __launch_bounds__(256) void k_S(float* __restrict__ ws) {
    int bid = blockIdx.x;            // E*E*32
    int pair = bid >> 5, ntile = bid & 31;
    int a = pair / E, b = pair % E;
    int tid = threadIdx.x;
    int tn = tid >> 4, tm = tid & 15;
    __shared__ float x1q[16][17], x2t[16][17];
    __shared__ float ka[16], bea[16], xs1[16], kb[16], beb[16], xs2[16];
    __shared__ float red[256];
    int n = ntile*16 + tn;
    {
        int r = tid >> 4, d0 = tid & 15;
        x1q[r][d0] = ws[OFF_X1Q + ((size_t)pair*N + ntile*16 + r)*D + d0];
        if (tid < 16) {
            int nn = ntile*16 + tid;
            ka[tid]  = ws[OFF_KVEC + a*N + nn];
            bea[tid] = ws[OFF_BETA + a*N + nn];
            xs1[tid] = ws[OFF_XS1 + (size_t)pair*N + nn];
        }
    }
    float acc = 0.f, accT = 0.f;
    const float* IKrow = ws + OFF_A + ((size_t)a*N + n)*N;
    for (int mt = 0; mt < 32; ++mt) {
        __syncthreads();
        int r = tid >> 4, d0 = tid & 15;
        x2t[r][d0] = ws[OFF_X1 + ((size_t)b*N + mt*16 + r)*D + d0];
        if (tid < 16) {
            int mmm = mt*16 + tid;
            kb[tid]  = ws[OFF_KVEC + b*N + mmm];
            beb[tid] = ws[OFF_BETA + b*N + mmm];
            xs2[tid] = ws[OFF_XS2 + (size_t)pair*N + mmm];
        }
        __syncthreads();
        float dot = 0.f;
        #pragma unroll
        for (int d = 0; d < D; ++d) dot += x1q[tn][d] * x2t[tm][d];
        float maha = 2.f*dot + xs1[tn] + xs2[tm];
        float Lv = __expf(ka[tn] + kb[tm] + maha);
        acc += bea[tn] * Lv * beb[tm];
        if (a == b) accT += IKrow[mt*16 + tm] * Lv;
    }
    red[tid] = acc; __syncthreads();
    for (int o = 128; o > 0; o >>= 1) { if (tid < o) red[tid] += red[tid+o]; __syncthreads(); }
    if (tid == 0) ws[OFF_SPART + bid] = red[0];
    if (a == b) {
        __syncthreads();
        red[tid] = accT; __syncthreads();
        for (int o = 128; o > 0; o >>= 1) { if (tid < o) red[tid] += red[tid+o]; __syncthreads(); }
        if (tid == 0) ws[OFF_TPART + a*32 + ntile] = red[0];
    }
}

// ---------- 8. finalize ----------
__global__ __launch_bounds__(256) void k_final(float* __restrict__ ws, const float* __restrict__ s,
                                               const float* __restrict__ os, float* __restrict__ out) {
    int tid = threadIdx.x;  // 256
    __shared__ float red[256];
    __shared__ float Msh[E], Vsh[E][D], cov[D][E+1];
    __shared__ float Sm[16][17], Si[16][17];

    for (int e = 0; e < E; ++e) {
        float p = 0.f;
        for (int n = tid; n < N; n += 256) p += ws[OFF_LB + e*N + n];
        red[tid] = p; __syncthreads();
        for (int o = 128; o > 0; o >>= 1) { if (tid < o) red[tid] += red[tid+o]; __syncthreads(); }
        if (tid == 0) Msh[e] = ws[OFF_C + e] * red[0];
        __syncthreads();
    }
    if (tid < E*D) {
        int e = tid / D, d = tid % D;
        float acc = 0.f;
        for (int n = 0; n < N; ++n)
            acc += ws[OFF_TIL + ((size_t)e*N + n)*D + d] * ws[OFF_LB + e*N + n];
        Vsh[e][d] = ws[OFF_C + e] * acc;
    }
    __syncthreads();

    if (tid < E*E) {
        int a = tid / E, bb = tid % E;
        float acc = 0.f;
        for (int q = 0; q < 32; ++q) acc += ws[OFF_SPART + (size_t)tid*32 + q];
        if (a == bb) {
            float tr = 0.f;
            for (int q = 0; q < 32; ++q) tr += ws[OFF_TPART + a*32 + q];
            acc -= tr;
        }
        acc *= ws[OFF_ISDR + tid];
        if (a == bb) acc += os[a];
        float v = acc - Msh[a]*Msh[bb];
        v *= ws[OFF_YSTD + a] * ws[OFF_YSTD + bb];
        out[E + tid] = v;                                // S
    }
    if (tid < E) out[tid] = Msh[tid]*ws[OFF_YSTD + tid] + ws[OFF_YMEAN + tid];  // Mout

    if (tid < D*E) {
        int d = tid / E, e = tid % E;
        float acc = 0.f;
        for (int k = 0; k < D; ++k) acc += ws[OFF_SSM + d*D + k] * Vsh[e][k];
        cov[d][e] = acc * ws[OFF_XSTD + d] * ws[OFF_YSTD + e];
    }
    int i = tid >> 4, j = tid & 15;
    Sm[i][j] = s[i*D + j];
    Si[i][j] = (i==j) ? 1.f : 0.f;
    __syncthreads();
    for (int k = 0; k < D; ++k) {
        float p   = Sm[k][k];
        float fik = Sm[i][k];
        float skj = Sm[k][j];
        float ikj = Si[k][j];
        __syncthreads();
        if (i == k) { Sm[k][j] = skj/p; Si[k][j] = ikj/p; }
        else        { float f = fik/p; Sm[i][j] -= f*skj; Si[i][j] -= f*ikj; }
        __syncthreads();
    }
    if (tid < D*E) {
        int d = tid / E, e = tid % E;
        float acc = 0.f;
        for (int k = 0; k < D; ++k) acc += Si[d][k] * cov[k][e];
        out[E + E*E + d*E + e] = acc;                    // Vout
    }
}

extern "C" void kernel_launch(void* const* d_in, const int* in_sizes, int n_in,
                              void* d_out, int out_size, void* d_ws, size_t ws_size,
                              hipStream_t stream) {
    const float* X     = (const float*)d_in[0];
    const float* Y     = (const float*)d_in[1];
    const float* m     = (const float*)d_in[2];
    const float* s     = (const float*)d_in[3];
    const float* ls    = (const float*)d_in[4];
    const float* os    = (const float*)d_in[5];
    const float* noise = (const float*)d_in[6];
    float* ws  = (float*)d_ws;
    float* out = (float*)d_out;

    k_prep  <<<1,       512, 0, stream>>>(X, Y, m, s, ws);
    k_buildA<<<E*32*32, 256, 0, stream>>>(ws, ls, os, noise);
    for (int kk = 0; kk < 8; ++kk) {
        k_panel<<<E, 256, 0, stream>>>(ws, kk*64);
        int nb = 7 - kk;
        if (nb > 0) {
            int ntiles = nb*(nb+1)/2;
            k_trail<<<E*ntiles, 256, 0, stream>>>(ws, kk*64);
        }
    }
    k_tinv_diag<<<E*8, 64, 0, stream>>>(ws);
    for (int d = 1; d < 8; ++d)
        k_tinv_off<<<E*(8-d), 256, 0, stream>>>(ws, d);
    k_syrk <<<E*36,      256, 0, stream>>>(ws);
    k_beta <<<E*N/256,   256, 0, stream>>>(ws);
    k_B    <<<E,         256, 0, stream>>>(ws, ls, os);
    k_R    <<<E*E,       256, 0, stream>>>(ws, ls);
    k_point<<<E*N/256,   256, 0, stream>>>(ws, ls, os);
    k_x1q  <<<E*E*N/256, 256, 0, stream>>>(ws);
    k_S    <<<E*E*32,    256, 0, stream>>>(ws);
    k_final<<<1,         256, 0, stream>>>(ws, s, os, out);
}